// Round 1
// baseline (57.048 us; speedup 1.0000x reference)
//
#include <hip/hip_runtime.h>
#include <stdint.h>

// Problem constants (from reference)
#define N_AG   8
#define T_DIM  128
#define B_DIM  64
#define S_SAMP 16
#define TB     8192      // T*B
#define DST    128       // D_STATE
#define E_DIM  64
#define HH_DIM 128
#define RPB    8         // tb-rows per block

// ---------------- JAX threefry2x32 (20 rounds) ----------------
__device__ __forceinline__ uint2 tf2x32(uint32_t k0, uint32_t k1,
                                        uint32_t c0, uint32_t c1) {
  uint32_t ks2 = k0 ^ k1 ^ 0x1BD11BDAu;
  uint32_t x0 = c0 + k0, x1 = c1 + k1;
#define TFR(r) { x0 += x1; x1 = (x1 << (r)) | (x1 >> (32 - (r))); x1 ^= x0; }
  TFR(13) TFR(15) TFR(26) TFR(6)
  x0 += k1;  x1 += ks2 + 1u;
  TFR(17) TFR(29) TFR(16) TFR(24)
  x0 += ks2; x1 += k0 + 2u;
  TFR(13) TFR(15) TFR(26) TFR(6)
  x0 += k0;  x1 += k1 + 3u;
  TFR(17) TFR(29) TFR(16) TFR(24)
  x0 += k1;  x1 += ks2 + 4u;
  TFR(13) TFR(15) TFR(26) TFR(6)
  x0 += ks2; x1 += k0 + 5u;
#undef TFR
  return make_uint2(x0, x1);
}

__global__ __launch_bounds__(256)
void alpha_fused_kernel(const float* __restrict__ q_vals,   // (8, 8192)
                        const float* __restrict__ states,   // (8192, 128)
                        const float* __restrict__ hw1_k1,   // (128,128)
                        const float* __restrict__ hw1_b1,   // (128)
                        const float* __restrict__ hw1_k2,   // (128,128)
                        const float* __restrict__ hw1_b2,   // (128)
                        const float* __restrict__ b1_k,     // (128,64)
                        const float* __restrict__ b1_b,     // (64)
                        const float* __restrict__ hw2_k1,   // (128,128)
                        const float* __restrict__ hw2_b1,   // (128)
                        const float* __restrict__ hw2_k2,   // (128,64)
                        const float* __restrict__ hw2_b2,   // (64)
                        const float* __restrict__ hb2_k1,   // (128,64)
                        const float* __restrict__ hb2_b1,   // (64)
                        const float* __restrict__ hb2_k2,   // (64,1)
                        const float* __restrict__ hb2_b2,   // (1)
                        float* __restrict__ out)            // (8, 8192)
{
  __shared__ float s_lds[RPB][DST];       // states rows            4 KB
  __shared__ float scratch[RPB][HH_DIM];  // h1 / h2                4 KB
  __shared__ float scratch2[RPB][E_DIM];  // hb                     2 KB
  __shared__ float w1_lds[RPB][2 * E_DIM];//                        4 KB
  __shared__ float b1_lds[RPB][E_DIM];    //                        2 KB
  __shared__ float w2_lds[RPB][E_DIM];    //                        2 KB
  __shared__ float b2_lds[RPB];
  __shared__ float q_lds[RPB][N_AG];
  __shared__ float cn_lds[RPB][S_SAMP][N_AG];  //                   4 KB
  __shared__ float red[RPB][S_SAMP * N_AG];    //                   4 KB

  const int tid  = threadIdx.x;
  const int row0 = blockIdx.x * RPB;

  // ---- load states (1024 floats) + q (64 floats) ----
  {
    const float4* src = reinterpret_cast<const float4*>(states + (size_t)row0 * DST);
    reinterpret_cast<float4*>(&s_lds[0][0])[tid] = src[tid];
  }
  if (tid < RPB * N_AG) {
    int r = tid >> 3, a = tid & 7;
    q_lds[r][a] = q_vals[a * TB + row0 + r];
  }
  __syncthreads();

  // ---- RNG: one thread per (row r, sample s); 128 threads ----
  if (tid < RPB * S_SAMP) {
    int r = tid >> 4, s = tid & 15;
    uint32_t j = (uint32_t)(row0 + r) * (uint32_t)S_SAMP + (uint32_t)s;
    // partitionable split: key_j = threefry(root=(0,42); 0, j)
    uint2 kj = tf2x32(0u, 42u, 0u, j);
    // _shuffle: key, subkey = split(key_j); subkey = threefry(key_j; 0, 1)
    uint2 sub = tf2x32(kj.x, kj.y, 0u, 1u);
    // sort keys: bits[i] = x0 ^ x1 of threefry(subkey; 0, i)
    uint32_t K[N_AG];
#pragma unroll
    for (int i = 0; i < N_AG; ++i) {
      uint2 b = tf2x32(sub.x, sub.y, 0u, (uint32_t)i);
      K[i] = b.x ^ b.y;
    }
    // perm[p] = index with p-th smallest key (stable); pos = perm
    int posa[N_AG];
#pragma unroll
    for (int i = 0; i < N_AG; ++i) {
      int rank = 0;
#pragma unroll
      for (int m = 0; m < N_AG; ++m)
        rank += (K[m] < K[i]) || (K[m] == K[i] && m < i);
      posa[rank] = i;
    }
    // coal_norm[a] = (sum_{a2: pos[a2] < pos[a]} q[a2]) / max(pos[a],1)
#pragma unroll
    for (int a = 0; a < N_AG; ++a) {
      int pa = posa[a];
      float cs = 0.f;
#pragma unroll
      for (int a2 = 0; a2 < N_AG; ++a2)
        cs += (posa[a2] < pa) ? q_lds[r][a2] : 0.f;
      cn_lds[r][s][a] = cs / (float)max(pa, 1);
    }
  }

  // ---- Phase 1: h1 = relu(s@hw1_k1 + b) [C=128]; b1 = s@b1_k + b [C=64] ----
  {
    int c = tid & 127, rg = tid >> 7;  // rows rg*4 .. rg*4+3
    float a0 = 0.f, a1 = 0.f, a2 = 0.f, a3 = 0.f;
#pragma unroll 4
    for (int k = 0; k < DST; ++k) {
      float wv = hw1_k1[k * HH_DIM + c];
      a0 += s_lds[rg * 4 + 0][k] * wv;
      a1 += s_lds[rg * 4 + 1][k] * wv;
      a2 += s_lds[rg * 4 + 2][k] * wv;
      a3 += s_lds[rg * 4 + 3][k] * wv;
    }
    float b = hw1_b1[c];
    scratch[rg * 4 + 0][c] = fmaxf(a0 + b, 0.f);
    scratch[rg * 4 + 1][c] = fmaxf(a1 + b, 0.f);
    scratch[rg * 4 + 2][c] = fmaxf(a2 + b, 0.f);
    scratch[rg * 4 + 3][c] = fmaxf(a3 + b, 0.f);
  }
  {
    int c = tid & 63, rg = tid >> 6;  // rows rg*2, rg*2+1
    float a0 = 0.f, a1 = 0.f;
#pragma unroll 4
    for (int k = 0; k < DST; ++k) {
      float wv = b1_k[k * E_DIM + c];
      a0 += s_lds[rg * 2 + 0][k] * wv;
      a1 += s_lds[rg * 2 + 1][k] * wv;
    }
    float b = b1_b[c];
    b1_lds[rg * 2 + 0][c] = a0 + b;
    b1_lds[rg * 2 + 1][c] = a1 + b;
  }
  __syncthreads();

  // ---- Phase 2: w1 = |h1@hw1_k2 + b| [C=128]; hb = relu(s@hb2_k1 + b) [C=64] ----
  {
    int c = tid & 127, rg = tid >> 7;
    float a0 = 0.f, a1 = 0.f, a2 = 0.f, a3 = 0.f;
#pragma unroll 4
    for (int k = 0; k < HH_DIM; ++k) {
      float wv = hw1_k2[k * (2 * E_DIM) + c];
      a0 += scratch[rg * 4 + 0][k] * wv;
      a1 += scratch[rg * 4 + 1][k] * wv;
      a2 += scratch[rg * 4 + 2][k] * wv;
      a3 += scratch[rg * 4 + 3][k] * wv;
    }
    float b = hw1_b2[c];
    w1_lds[rg * 4 + 0][c] = fabsf(a0 + b);
    w1_lds[rg * 4 + 1][c] = fabsf(a1 + b);
    w1_lds[rg * 4 + 2][c] = fabsf(a2 + b);
    w1_lds[rg * 4 + 3][c] = fabsf(a3 + b);
  }
  {
    int c = tid & 63, rg = tid >> 6;
    float a0 = 0.f, a1 = 0.f;
#pragma unroll 4
    for (int k = 0; k < DST; ++k) {
      float wv = hb2_k1[k * E_DIM + c];
      a0 += s_lds[rg * 2 + 0][k] * wv;
      a1 += s_lds[rg * 2 + 1][k] * wv;
    }
    float b = hb2_b1[c];
    scratch2[rg * 2 + 0][c] = fmaxf(a0 + b, 0.f);
    scratch2[rg * 2 + 1][c] = fmaxf(a1 + b, 0.f);
  }
  __syncthreads();

  // ---- Phase 3: h2 = relu(s@hw2_k1 + b) [C=128, overwrite scratch];
  //               b2[r] = hb@hb2_k2 + b (wave-0 shuffle reduce) ----
  {
    int c = tid & 127, rg = tid >> 7;
    float a0 = 0.f, a1 = 0.f, a2 = 0.f, a3 = 0.f;
#pragma unroll 4
    for (int k = 0; k < DST; ++k) {
      float wv = hw2_k1[k * HH_DIM + c];
      a0 += s_lds[rg * 4 + 0][k] * wv;
      a1 += s_lds[rg * 4 + 1][k] * wv;
      a2 += s_lds[rg * 4 + 2][k] * wv;
      a3 += s_lds[rg * 4 + 3][k] * wv;
    }
    float b = hw2_b1[c];
    float h0 = fmaxf(a0 + b, 0.f), h1v = fmaxf(a1 + b, 0.f);
    float h2v = fmaxf(a2 + b, 0.f), h3 = fmaxf(a3 + b, 0.f);
    // NOTE: scratch still holds h1 until the preceding barrier; safe to
    // overwrite now (phase-2 readers are past __syncthreads()).
    scratch[rg * 4 + 0][c] = h0;
    scratch[rg * 4 + 1][c] = h1v;
    scratch[rg * 4 + 2][c] = h2v;
    scratch[rg * 4 + 3][c] = h3;
  }
  if (tid < 64) {
    float k2v = hb2_k2[tid];
    float bias = hb2_b2[0];
#pragma unroll
    for (int r = 0; r < RPB; ++r) {
      float v = scratch2[r][tid] * k2v;
      for (int off = 32; off > 0; off >>= 1) v += __shfl_down(v, off, 64);
      if (tid == 0) b2_lds[r] = v + bias;
    }
  }
  __syncthreads();

  // ---- Phase 4: w2 = |h2@hw2_k2 + b| [C=64] ----
  {
    int c = tid & 63, rg = tid >> 6;
    float a0 = 0.f, a1 = 0.f;
#pragma unroll 4
    for (int k = 0; k < HH_DIM; ++k) {
      float wv = hw2_k2[k * E_DIM + c];
      a0 += scratch[rg * 2 + 0][k] * wv;
      a1 += scratch[rg * 2 + 1][k] * wv;
    }
    float b = hw2_b2[c];
    w2_lds[rg * 2 + 0][c] = fabsf(a0 + b);
    w2_lds[rg * 2 + 1][c] = fabsf(a1 + b);
  }
  __syncthreads();

  // ---- Main: y(r,s,a) = sum_e elu(cn*w1a + q*w1b + b1) * w2 + b2 ----
  {
    int pair = tid & 127;            // (s,a)
    int s = pair >> 3, a = pair & 7;
    int rg = tid >> 7;               // rows rg*4 .. rg*4+3
#pragma unroll
    for (int rr = 0; rr < 4; ++rr) {
      int r = rg * 4 + rr;
      float cn  = cn_lds[r][s][a];
      float qv  = q_lds[r][a];
      float y   = 0.f;
#pragma unroll 8
      for (int e = 0; e < E_DIM; ++e) {
        float h = fmaf(cn, w1_lds[r][e], fmaf(qv, w1_lds[r][E_DIM + e], b1_lds[r][e]));
        float eh = __expf(h) - 1.0f;           // elu negative branch
        float act = (h > 0.f) ? h : eh;
        y = fmaf(act, w2_lds[r][e], y);
      }
      red[r][pair] = fabsf(y + b2_lds[r]);
    }
  }
  __syncthreads();

  // ---- Reduce over samples, write out[a][row] ----
  if (tid < RPB * N_AG) {
    int r = tid >> 3, a = tid & 7;
    float acc = 0.f;
#pragma unroll
    for (int ss = 0; ss < S_SAMP; ++ss) acc += red[r][ss * 8 + a];
    out[a * TB + row0 + r] = acc * (1.0f / (float)S_SAMP);
  }
}

extern "C" void kernel_launch(void* const* d_in, const int* in_sizes, int n_in,
                              void* d_out, int out_size, void* d_ws, size_t ws_size,
                              hipStream_t stream) {
  const float* q_vals = (const float*)d_in[0];
  const float* states = (const float*)d_in[1];
  const float* hw1_k1 = (const float*)d_in[2];
  const float* hw1_b1 = (const float*)d_in[3];
  const float* hw1_k2 = (const float*)d_in[4];
  const float* hw1_b2 = (const float*)d_in[5];
  const float* b1_k   = (const float*)d_in[6];
  const float* b1_b   = (const float*)d_in[7];
  const float* hw2_k1 = (const float*)d_in[8];
  const float* hw2_b1 = (const float*)d_in[9];
  const float* hw2_k2 = (const float*)d_in[10];
  const float* hw2_b2 = (const float*)d_in[11];
  const float* hb2_k1 = (const float*)d_in[12];
  const float* hb2_b1 = (const float*)d_in[13];
  const float* hb2_k2 = (const float*)d_in[14];
  const float* hb2_b2 = (const float*)d_in[15];
  float* out = (float*)d_out;

  dim3 grid(TB / RPB);   // 1024 blocks
  dim3 block(256);
  alpha_fused_kernel<<<grid, block, 0, stream>>>(
      q_vals, states, hw1_k1, hw1_b1, hw1_k2, hw1_b2, b1_k, b1_b,
      hw2_k1, hw2_b1, hw2_k2, hw2_b2, hb2_k1, hb2_b1, hb2_k2, hb2_b2, out);
}